// Round 1
// baseline (668.409 us; speedup 1.0000x reference)
//
#include <hip/hip_runtime.h>
#include <hip/hip_bf16.h>

// Logic-gate network: 23 layers, widths [128]*16 + [64,32,16,8,4,2,1].
// Node j: out = c0 + c1*a + c2*b + c3*a*b, a=h[ia[j]], b=h[ib[j]],
// c = softmax(W[j]) @ GATE_COEFFS  (temperature = 1).
// N_CELLS = 262144 independent "cells" (rows).

#define N_CELLS   262144
#define TOTAL_NODES 2175
#define NLAYER    23
#define CELLS     64          // cells per block
#define BLOCK     256         // threads per block (4 waves; wave q = node-quarter q)

__device__ const int LAYER_OFF[NLAYER + 1] = {
    0, 128, 256, 384, 512, 640, 768, 896, 1024, 1152, 1280, 1408,
    1536, 1664, 1792, 1920, 2048, 2112, 2144, 2160, 2168, 2172, 2174, 2175
};

__device__ const float GC[16][4] = {
    {0, 0, 0, 0}, {0, 0, 0, 1}, {0, 1, 0, -1}, {0, 1, 0, 0},
    {0, 0, 1, -1}, {0, 0, 1, 0}, {0, 1, 1, -2}, {0, 1, 1, -1},
    {1, -1, -1, 1}, {1, -1, -1, 2}, {1, 0, -1, 0}, {1, 0, -1, 1},
    {1, -1, 0, 0}, {1, -1, 0, 1}, {1, 0, 0, -1}, {1, 0, 0, 0}
};

// ---- Kernel A: per-node gate coefficients: c = softmax(W[node]) @ GC ----
__global__ void coeff_kernel(const float* __restrict__ W, float4* __restrict__ cout) {
    int node = blockIdx.x * blockDim.x + threadIdx.x;
    if (node >= TOTAL_NODES) return;
    const float* w = W + node * 16;
    float v[16];
    float m = -1e30f;
    #pragma unroll
    for (int i = 0; i < 16; ++i) { v[i] = w[i]; m = fmaxf(m, v[i]); }
    float s = 0.f;
    #pragma unroll
    for (int i = 0; i < 16; ++i) { v[i] = expf(v[i] - m); s += v[i]; }
    float inv = 1.0f / s;
    float c0 = 0.f, c1 = 0.f, c2 = 0.f, c3 = 0.f;
    #pragma unroll
    for (int i = 0; i < 16; ++i) {
        float p = v[i] * inv;
        c0 += p * GC[i][0];
        c1 += p * GC[i][1];
        c2 += p * GC[i][2];
        c3 += p * GC[i][3];
    }
    cout[node] = make_float4(c0, c1, c2, c3);
}

// ---- Kernel B: the network. One block = 64 cells; LDS ping-pong [2][128][64]. ----
__global__ __launch_bounds__(BLOCK, 2)
void net_kernel(const float* __restrict__ x,
                const int* __restrict__ idx_a,
                const int* __restrict__ idx_b,
                const float4* __restrict__ coeffs,
                float* __restrict__ out) {
    // 2 * 128 * 64 * 4B = 64 KB static LDS -> 2 blocks/CU (8 waves/CU).
    __shared__ float buf[2][128][CELLS];

    const int t    = threadIdx.x;
    const int cell = t & 63;        // lane within wave = cell
    const int q    = t >> 6;        // wave id = node-quarter
    const size_t base = (size_t)blockIdx.x * CELLS;

    // Stage x (64 cells x 16 f32 = 4 KB) transposed into buf[0][k][cell].
    {
        const float4* xv = reinterpret_cast<const float4*>(x + base * 16);
        float4 v = xv[t];           // coalesced: 256 float4 = 1024 floats
        int c = t >> 2;             // cell
        int k = (t & 3) << 2;       // feature base
        buf[0][k + 0][c] = v.x;
        buf[0][k + 1][c] = v.y;
        buf[0][k + 2][c] = v.z;
        buf[0][k + 3][c] = v.w;
    }
    __syncthreads();

    int cur = 0;
    for (int li = 0; li < NLAYER; ++li) {
        const int off = LAYER_OFF[li];
        const int w   = LAYER_OFF[li + 1] - off;
        const int per = (w + 3) >> 2;       // nodes per wave
        const int n0  = q * per;
        const int n1  = min(w, n0 + per);

        const float (* __restrict__ rb)[CELLS] = buf[cur];
        float (* __restrict__ wb)[CELLS] = buf[cur ^ 1];

        #pragma unroll 4
        for (int n = n0; n < n1; ++n) {
            int nu = __builtin_amdgcn_readfirstlane(n);   // wave-uniform -> scalar loads
            int g  = off + nu;
            int ia = idx_a[g];
            int ib = idx_b[g];
            float4 cf = coeffs[g];
            float a = rb[ia][cell];
            float b = rb[ib][cell];
            wb[nu][cell] = cf.x + cf.y * a + cf.z * b + cf.w * (a * b);
        }
        __syncthreads();
        cur ^= 1;
    }

    if (t < CELLS) out[base + t] = buf[cur][0][t];
}

extern "C" void kernel_launch(void* const* d_in, const int* in_sizes, int n_in,
                              void* d_out, int out_size, void* d_ws, size_t ws_size,
                              hipStream_t stream) {
    const float* x  = (const float*)d_in[0];
    const float* W  = (const float*)d_in[1];
    const int*   ia = (const int*)d_in[2];
    const int*   ib = (const int*)d_in[3];
    float4* coeffs  = (float4*)d_ws;   // 2175 * 16 B = 34.8 KB scratch

    coeff_kernel<<<(TOTAL_NODES + 255) / 256, 256, 0, stream>>>(W, coeffs);

    const int grid = N_CELLS / CELLS;  // 4096 blocks
    net_kernel<<<grid, BLOCK, 0, stream>>>(x, ia, ib, coeffs, (float*)d_out);
}

// Round 3
// 272.215 us; speedup vs baseline: 2.4554x; 2.4554x over previous
//
#include <hip/hip_runtime.h>
#include <hip/hip_fp16.h>
#include <hip/hip_bf16.h>

// Logic-gate network: 23 layers, widths [128]*16 + [64,32,16,8,4,2,1].
// Node j: out = c0 + c1*a + c2*b + c3*a*b; c = softmax(W[j]) @ GATE_COEFFS.
// N_CELLS = 262144 independent cells.
//
// R2 design: fp16 STORAGE (2 cells packed per dword, halves LDS inst count),
// fp32 math (precision headroom: values provably in [0,1], per-layer RNE
// repack error <= 2.44e-4, worst-case 23*2.44e-4 = 5.6e-3 < 9.26e-3 thr).
// 512 threads / 8 waves, 64KB LDS ping-pong -> 2 blocks/CU = 16 waves/CU.

#define N_CELLS     262144
#define TOTAL_NODES 2175
#define NLAYER      23
#define CELLS       128        // cells per block (64 lanes x 2 packed)
#define BLOCK       512        // 8 waves; wave q = node-octant q
#define ROWS        128        // max layer width

__device__ const int LAYER_OFF[NLAYER + 1] = {
    0, 128, 256, 384, 512, 640, 768, 896, 1024, 1152, 1280, 1408,
    1536, 1664, 1792, 1920, 2048, 2112, 2144, 2160, 2168, 2172, 2174, 2175
};

__device__ const float GC[16][4] = {
    {0, 0, 0, 0}, {0, 0, 0, 1}, {0, 1, 0, -1}, {0, 1, 0, 0},
    {0, 0, 1, -1}, {0, 0, 1, 0}, {0, 1, 1, -2}, {0, 1, 1, -1},
    {1, -1, -1, 1}, {1, -1, -1, 2}, {1, 0, -1, 0}, {1, 0, -1, 1},
    {1, -1, 0, 0}, {1, -1, 0, 1}, {1, 0, 0, -1}, {1, 0, 0, 0}
};

// 32B node descriptor: one scalar-load stream per node in the hot loop.
struct __align__(32) NodeDesc {
    float c0, c1, c2, c3;
    int   ia, ib;
    int   pad0, pad1;
};

// ---- Kernel A: build per-node descriptors: c = softmax(W[node]) @ GC ----
__global__ void coeff_kernel(const float* __restrict__ W,
                             const int* __restrict__ idx_a,
                             const int* __restrict__ idx_b,
                             NodeDesc* __restrict__ dout) {
    int node = blockIdx.x * blockDim.x + threadIdx.x;
    if (node >= TOTAL_NODES) return;
    const float* w = W + node * 16;
    float v[16];
    float m = -1e30f;
    #pragma unroll
    for (int i = 0; i < 16; ++i) { v[i] = w[i]; m = fmaxf(m, v[i]); }
    float s = 0.f;
    #pragma unroll
    for (int i = 0; i < 16; ++i) { v[i] = expf(v[i] - m); s += v[i]; }
    float inv = 1.0f / s;
    float c0 = 0.f, c1 = 0.f, c2 = 0.f, c3 = 0.f;
    #pragma unroll
    for (int i = 0; i < 16; ++i) {
        float p = v[i] * inv;
        c0 += p * GC[i][0];
        c1 += p * GC[i][1];
        c2 += p * GC[i][2];
        c3 += p * GC[i][3];
    }
    NodeDesc d;
    d.c0 = c0; d.c1 = c1; d.c2 = c2; d.c3 = c3;
    d.ia = idx_a[node]; d.ib = idx_b[node];
    d.pad0 = 0; d.pad1 = 0;
    dout[node] = d;
}

// ---- Kernel B: the network. 128 cells/block; LDS ping-pong of packed half2. ----
__global__ __launch_bounds__(BLOCK, 4)
void net_kernel(const float* __restrict__ x,
                const NodeDesc* __restrict__ desc,
                float* __restrict__ out) {
    // 2 * 128 rows * 64 lanes * 4B = 64 KB -> 2 blocks/CU (16 waves/CU).
    __shared__ unsigned int buf[2][ROWS][64];

    const int t    = threadIdx.x;
    const int lane = t & 63;        // lane = cell pair (cells lane, lane+64)
    const int q    = t >> 6;        // wave id = node-octant
    const size_t base = (size_t)blockIdx.x * CELLS;

    // Stage x (128 cells x 16 f32) -> packed half2 buf[0][k][cell&63].
    {
        const float4* xv = reinterpret_cast<const float4*>(x + base * 16);
        float4 v = xv[t];                 // coalesced: 512 float4 = 2048 floats
        int c  = t >> 2;                  // cell 0..127
        int k  = (t & 3) << 2;            // feature base
        int hl = c >> 6;                  // 0 = lo half, 1 = hi half
        int cl = c & 63;
        __half* hp = reinterpret_cast<__half*>(&buf[0][0][0]);
        hp[((k + 0) * 64 + cl) * 2 + hl] = __float2half(v.x);
        hp[((k + 1) * 64 + cl) * 2 + hl] = __float2half(v.y);
        hp[((k + 2) * 64 + cl) * 2 + hl] = __float2half(v.z);
        hp[((k + 3) * 64 + cl) * 2 + hl] = __float2half(v.w);
    }
    __syncthreads();

    int cur = 0;
    for (int li = 0; li < NLAYER; ++li) {
        const int off = LAYER_OFF[li];
        const int w   = LAYER_OFF[li + 1] - off;
        const int per = (w + 7) >> 3;       // nodes per wave (8 waves)
        const int n0  = q * per;
        const int n1  = min(w, n0 + per);

        const unsigned int (* __restrict__ rb)[64] = buf[cur];
        unsigned int (* __restrict__ wb)[64] = buf[cur ^ 1];

        #pragma unroll 4
        for (int n = n0; n < n1; ++n) {
            int nu = __builtin_amdgcn_readfirstlane(n);   // wave-uniform
            NodeDesc d = desc[off + nu];                  // scalar loads
            unsigned int ap = rb[d.ia][lane];
            unsigned int bp = rb[d.ib][lane];
            float2 af = __half22float2(*reinterpret_cast<__half2*>(&ap));
            float2 bf = __half22float2(*reinterpret_cast<__half2*>(&bp));
            float lo = d.c0 + d.c1 * af.x + d.c2 * bf.x + d.c3 * (af.x * bf.x);
            float hi = d.c0 + d.c1 * af.y + d.c2 * bf.y + d.c3 * (af.y * bf.y);
            __half2 r = __floats2half2_rn(lo, hi);
            wb[nu][lane] = *reinterpret_cast<unsigned int*>(&r);
        }
        __syncthreads();
        cur ^= 1;
    }

    // Final layer width 1: row 0 holds packed (cell lane, cell lane+64).
    if (t < 64) {
        unsigned int p = buf[cur][0][t];
        __half2 h = *reinterpret_cast<__half2*>(&p);
        out[base + t]      = __low2float(h);
        out[base + 64 + t] = __high2float(h);
    }
}

extern "C" void kernel_launch(void* const* d_in, const int* in_sizes, int n_in,
                              void* d_out, int out_size, void* d_ws, size_t ws_size,
                              hipStream_t stream) {
    const float* x  = (const float*)d_in[0];
    const float* W  = (const float*)d_in[1];
    const int*   ia = (const int*)d_in[2];
    const int*   ib = (const int*)d_in[3];
    NodeDesc* desc  = (NodeDesc*)d_ws;   // 2175 * 32 B = 69.6 KB scratch

    coeff_kernel<<<(TOTAL_NODES + 255) / 256, 256, 0, stream>>>(W, ia, ib, desc);

    const int grid = N_CELLS / CELLS;    // 2048 blocks
    net_kernel<<<grid, BLOCK, 0, stream>>>(x, desc, (float*)d_out);
}

// Round 4
// 176.893 us; speedup vs baseline: 3.7786x; 1.5389x over previous
//
#include <hip/hip_runtime.h>
#include <hip/hip_fp16.h>
#include <hip/hip_bf16.h>

// Logic-gate network: 23 layers, widths [128]*16 + [64,32,16,8,4,2,1].
// Node j: out = c0 + c1*a + c2*b + c3*a*b; c = softmax(W[j]) @ GATE_COEFFS.
// N_CELLS = 262144 independent cells.
//
// R4: single 32KB LDS buffer + 2 barriers/layer (read->regs, bar, write, bar)
// -> 4 blocks/CU = 32 waves/CU (was 16). fp16 storage / fp32 math (absmax
// 1.95e-3 measured, thr 9.26e-3). 3-FMA polynomial. VGPR capped at 64 via
// __launch_bounds__(512, 8); results in statically-indexed res[PER].

#define N_CELLS     262144
#define TOTAL_NODES 2175
#define NLAYER      23
#define CELLS       128        // cells per block (64 lanes x 2 packed fp16)
#define BLOCK       512        // 8 waves; wave q owns PER nodes per layer
#define ROWS        128        // max layer width

__device__ const float GC[16][4] = {
    {0, 0, 0, 0}, {0, 0, 0, 1}, {0, 1, 0, -1}, {0, 1, 0, 0},
    {0, 0, 1, -1}, {0, 0, 1, 0}, {0, 1, 1, -2}, {0, 1, 1, -1},
    {1, -1, -1, 1}, {1, -1, -1, 2}, {1, 0, -1, 0}, {1, 0, -1, 1},
    {1, -1, 0, 0}, {1, -1, 0, 1}, {1, 0, 0, -1}, {1, 0, 0, 0}
};

// 32B node descriptor: one wave-uniform scalar-load stream in the hot loop.
struct __align__(32) NodeDesc {
    float c0, c1, c2, c3;
    int   ia, ib;
    int   pad0, pad1;
};

// ---- Kernel A: build per-node descriptors: c = softmax(W[node]) @ GC ----
__global__ void coeff_kernel(const float* __restrict__ W,
                             const int* __restrict__ idx_a,
                             const int* __restrict__ idx_b,
                             NodeDesc* __restrict__ dout) {
    int node = blockIdx.x * blockDim.x + threadIdx.x;
    if (node >= TOTAL_NODES) return;
    const float* w = W + node * 16;
    float v[16];
    float m = -1e30f;
    #pragma unroll
    for (int i = 0; i < 16; ++i) { v[i] = w[i]; m = fmaxf(m, v[i]); }
    float s = 0.f;
    #pragma unroll
    for (int i = 0; i < 16; ++i) { v[i] = expf(v[i] - m); s += v[i]; }
    float inv = 1.0f / s;
    float c0 = 0.f, c1 = 0.f, c2 = 0.f, c3 = 0.f;
    #pragma unroll
    for (int i = 0; i < 16; ++i) {
        float p = v[i] * inv;
        c0 += p * GC[i][0];
        c1 += p * GC[i][1];
        c2 += p * GC[i][2];
        c3 += p * GC[i][3];
    }
    NodeDesc d;
    d.c0 = c0; d.c1 = c1; d.c2 = c2; d.c3 = c3;
    d.ia = idx_a[node]; d.ib = idx_b[node];
    d.pad0 = 0; d.pad1 = 0;
    dout[node] = d;
}

// One layer: wave q computes nodes [q*PER, q*PER+PER) of this layer.
// Phase 1: gather operands + compute into res[] (regs). Barrier.
// Phase 2: write res[] back over the (now dead) input rows. Barrier.
template<int PER>
__device__ __forceinline__ void layer_step(const NodeDesc* __restrict__ desc,
                                           int off, int w,
                                           unsigned int (* __restrict__ buf)[64],
                                           int q, int lane) {
    const int n0 = q * PER;
    unsigned int res[PER];
    const bool active = (PER > 1) || (n0 < w);   // tail layers idle some waves

    if (active) {
        #pragma unroll
        for (int j = 0; j < PER; ++j) {
            int nu = __builtin_amdgcn_readfirstlane(n0 + j);
            NodeDesc d = desc[off + nu];          // scalar loads (s_load_dwordx8)
            unsigned int ap = buf[d.ia][lane];
            unsigned int bp = buf[d.ib][lane];
            float2 af = __half22float2(*reinterpret_cast<__half2*>(&ap));
            float2 bf = __half22float2(*reinterpret_cast<__half2*>(&bp));
            // out = c0 + c1*a + c2*b + c3*ab = a*(c1 + c3*b) + (c0 + c2*b)
            float lo = fmaf(af.x, fmaf(d.c3, bf.x, d.c1), fmaf(d.c2, bf.x, d.c0));
            float hi = fmaf(af.y, fmaf(d.c3, bf.y, d.c1), fmaf(d.c2, bf.y, d.c0));
            __half2 r = __floats2half2_rn(lo, hi);
            res[j] = *reinterpret_cast<unsigned int*>(&r);
        }
    }
    __syncthreads();                              // all reads done
    if (active) {
        #pragma unroll
        for (int j = 0; j < PER; ++j) {
            int nu = __builtin_amdgcn_readfirstlane(n0 + j);
            buf[nu][lane] = res[j];
        }
    }
    __syncthreads();                              // all writes done
}

// ---- Kernel B: the network. 128 cells/block; single 32KB LDS buffer. ----
__global__ __launch_bounds__(BLOCK, 8)
void net_kernel(const float* __restrict__ x,
                const NodeDesc* __restrict__ desc,
                float* __restrict__ out) {
    // 128 rows * 64 lanes * 4B = 32 KB -> 4 blocks/CU (32 waves/CU).
    __shared__ unsigned int buf[ROWS][64];

    const int t    = threadIdx.x;
    const int lane = t & 63;        // lane = cell pair (cells lane, lane+64)
    const int q    = t >> 6;        // wave id
    const size_t base = (size_t)blockIdx.x * CELLS;

    // Stage x (128 cells x 16 f32) -> packed half2 buf[k][cell&63].
    {
        const float4* xv = reinterpret_cast<const float4*>(x + base * 16);
        float4 v = xv[t];                 // coalesced: 512 float4 = 2048 floats
        int c  = t >> 2;                  // cell 0..127
        int k  = (t & 3) << 2;            // feature base
        int hl = c >> 6;                  // 0 = lo half, 1 = hi half
        int cl = c & 63;
        __half* hp = reinterpret_cast<__half*>(&buf[0][0]);
        hp[((k + 0) * 64 + cl) * 2 + hl] = __float2half(v.x);
        hp[((k + 1) * 64 + cl) * 2 + hl] = __float2half(v.y);
        hp[((k + 2) * 64 + cl) * 2 + hl] = __float2half(v.z);
        hp[((k + 3) * 64 + cl) * 2 + hl] = __float2half(v.w);
    }
    __syncthreads();

    // Layers 0..15: width 128, PER=16.
    #pragma unroll 1
    for (int li = 0; li < 16; ++li)
        layer_step<16>(desc, li * 128, 128, buf, q, lane);
    // Tail: widths 64,32,16,8,4,2,1.
    layer_step<8>(desc, 2048, 64, buf, q, lane);
    layer_step<4>(desc, 2112, 32, buf, q, lane);
    layer_step<2>(desc, 2144, 16, buf, q, lane);
    layer_step<1>(desc, 2160,  8, buf, q, lane);
    layer_step<1>(desc, 2168,  4, buf, q, lane);
    layer_step<1>(desc, 2172,  2, buf, q, lane);
    layer_step<1>(desc, 2174,  1, buf, q, lane);

    // Final layer width 1: row 0 holds packed (cell lane, cell lane+64).
    if (t < 64) {
        unsigned int p = buf[0][t];
        __half2 h = *reinterpret_cast<__half2*>(&p);
        out[base + t]      = __low2float(h);
        out[base + 64 + t] = __high2float(h);
    }
}

extern "C" void kernel_launch(void* const* d_in, const int* in_sizes, int n_in,
                              void* d_out, int out_size, void* d_ws, size_t ws_size,
                              hipStream_t stream) {
    const float* x  = (const float*)d_in[0];
    const float* W  = (const float*)d_in[1];
    const int*   ia = (const int*)d_in[2];
    const int*   ib = (const int*)d_in[3];
    NodeDesc* desc  = (NodeDesc*)d_ws;   // 2175 * 32 B = 69.6 KB scratch

    coeff_kernel<<<(TOTAL_NODES + 255) / 256, 256, 0, stream>>>(W, ia, ib, desc);

    const int grid = N_CELLS / CELLS;    // 2048 blocks
    net_kernel<<<grid, BLOCK, 0, stream>>>(x, desc, (float*)d_out);
}